// Round 8
// baseline (263.384 us; speedup 1.0000x reference)
//
#include <hip/hip_runtime.h>

#define DIM 160
#define SLICE (DIM * DIM)
#define TH 16
#define TW 16
#define CD 32                 // output slices per chunk; 5 chunks per batch
#define NCHUNK (DIM / CD)     // 5
#define WSTR 20
#define WPL 484               // 24 rows * 20 + 4 (plane-offset pad: rotates bank groups across c)
#define WBUFSZ (5 * WPL)      // 2420 floats per parity buffer (9.68 KB)
#define USTR 20
#define UPL 324               // 16 rows * 20 + 4
#define UBUFSZ (5 * UPL)      // 1620 floats per parity buffer (6.48 KB)

// Fused LNCC, separable order w -> h -> d; products never touch LDS.
// Software pipeline, ONE barrier per input slice, parity double-buffered:
//   region(zi):  [A]  240 thr: unit (c, halo-row, w-half). 16 x/y floats from
//                     GLOBAL (4 b128; L1/L2 dedup the x/y overlap across c),
//                     products in regs, 9-tap w-slide -> W[zi&1] (2 b128).
//                [S2] 40 thr: 9-tap h-sum W[(zi-1)&1] -> U[(zi-1)&1]
//                     (23 b128 reads + 8 writes, register slide).
//                [S4] 256 thr: one output column each; 9-deep register d-ring
//                     (compile-time phase via 9-unrolled loop) from
//                     U[(zi-2)&1]; ncc emit.
//                __syncthreads()
// Hazards: each buffer's writer/readers are 2 regions apart = separated by a
// barrier; same-region roles touch opposite parities.
__global__ __launch_bounds__(256, 4)
void lncc_kernel(const float* __restrict__ x, const float* __restrict__ y,
                 float* __restrict__ out)
{
    __shared__ __align__(16) float Wb[2 * WBUFSZ];
    __shared__ __align__(16) float Ub[2 * UBUFSZ];
    __shared__ float wsum[4];

    const int t  = threadIdx.x;
    const int w0 = blockIdx.x * TW;
    const int h0 = blockIdx.y * TH;
    const int bz = blockIdx.z;
    const int b   = bz / NCHUNK;
    const int zo0 = (bz % NCHUNK) * CD;

    const float* xb = x + (size_t)b * (DIM * SLICE);
    const float* yb = y + (size_t)b * (DIM * SLICE);

    // ---- role A: (cA, rowA, whA) ----
    const bool isA = t < 240;
    const int cA   = t / 48;              // 0..4
    const int rA   = t % 48;
    const int rowA = rA >> 1;             // 0..23 halo row
    const int whA  = rA & 1;              // w-half: outputs whA*8 .. whA*8+7
    const int ghA  = min(max(h0 - 4 + rowA, 0), DIM - 1);
    const int wsA  = w0 - 4 + 8 * whA;    // first of 16 loaded floats (16B-aligned)
    const bool fastA = (wsA >= 0) && (wsA + 15 < DIM);
    const bool needX = (cA == 0) | (cA == 2) | (cA == 4);
    const bool needY = (cA == 1) | (cA == 3) | (cA == 4);

    // ---- role S2: (cS, wqS, h8S) ----
    const bool isS2 = t < 40;
    const int cS  = t / 8;                // 0..4
    const int rS  = t % 8;
    const int wqS = (rS >> 1) * 4;        // 0,4,8,12
    const int h8S = (rS & 1) * 8;         // 0 or 8

    // ---- role S4: one output (h,w) column each ----
    const int i4 = t >> 4;
    const int j4 = t & 15;

    float hist[9][5];                     // register d-ring (const indices)
    float rs[5] = {0.f, 0.f, 0.f, 0.f, 0.f};
    float acc = 0.f;

    auto load16 = [&](const float* arr, int z, float v[16]) {
        const float* row = arr + (size_t)z * SLICE + (size_t)ghA * DIM;
        if (fastA) {
            #pragma unroll
            for (int g = 0; g < 4; ++g) {
                const float4 q = *reinterpret_cast<const float4*>(row + wsA + 4 * g);
                v[4*g+0] = q.x; v[4*g+1] = q.y; v[4*g+2] = q.z; v[4*g+3] = q.w;
            }
        } else {
            #pragma unroll
            for (int m = 0; m < 16; ++m)
                v[m] = row[min(max(wsA + m, 0), DIM - 1)];
        }
    };

    const int zlast = zo0 + CD + 3;       // last input slice (pre-clamp index)
    const int zend  = zlast + 2;          // pipeline drain
    for (int base = zo0 - 4; base <= zend; base += 9) {
        #pragma unroll
        for (int p = 0; p < 9; ++p) {     // (zi - (zo0-4)) % 9 == p
            const int zi = base + p;
            if (zi <= zend) {
                // ---- A: issue global loads early ----
                float vx[16], vy[16];
                const bool doA = isA && (zi <= zlast);
                if (doA) {
                    const int zA = min(max(zi, 0), DIM - 1);
                    if (needX) load16(xb, zA, vx);
                    if (needY) load16(yb, zA, vy);
                }

                // ---- S2: h-sum W[(zi-1)&1] -> U[(zi-1)&1] ----
                if (isS2 && (zi - 1 >= zo0 - 4) && (zi - 1 <= zlast)) {
                    const float* Ws = &Wb[((zi - 1) & 1) * WBUFSZ + cS * WPL];
                    float*       Ud = &Ub[((zi - 1) & 1) * UBUFSZ + cS * UPL];
                    float4 s = {0, 0, 0, 0};
                    #pragma unroll
                    for (int k = 0; k < 9; ++k)
                        s += *reinterpret_cast<const float4*>(&Ws[(h8S + k) * WSTR + wqS]);
                    *reinterpret_cast<float4*>(&Ud[h8S * USTR + wqS]) = s;
                    #pragma unroll
                    for (int u = 1; u < 8; ++u) {
                        s += *reinterpret_cast<const float4*>(&Ws[(h8S + u + 8) * WSTR + wqS])
                           - *reinterpret_cast<const float4*>(&Ws[(h8S + u - 1) * WSTR + wqS]);
                        *reinterpret_cast<float4*>(&Ud[(h8S + u) * USTR + wqS]) = s;
                    }
                }

                // ---- S4: register d-ring from U[(zi-2)&1] ----
                if (zi - 2 >= zo0 - 4) {
                    const float* Us = &Ub[((zi - 2) & 1) * UBUFSZ];
                    const int psr = (p + 7) % 9;      // phase of slice zi-2
                    #pragma unroll
                    for (int c = 0; c < 5; ++c) {
                        const float u = Us[c * UPL + i4 * USTR + j4];
                        rs[c] += u;
                        hist[psr][c] = u;
                    }
                    if (zi - 2 >= zo0 + 4) {
                        const float inv = 1.0f / 729.0f;
                        const float xm = rs[0] * inv, ym = rs[1] * inv;
                        const float x2 = rs[2] * inv, y2 = rs[3] * inv;
                        const float xy = rs[4] * inv;
                        const float cross = xy - xm * ym;
                        const float vx_ = x2 - xm * xm;
                        const float vy_ = y2 - ym * ym;
                        acc += cross * cross / (vx_ * vy_ + 1e-5f);
                        const int po = (psr + 1) % 9; // slice (zi-2)-8 leaves
                        #pragma unroll
                        for (int c = 0; c < 5; ++c)
                            rs[c] -= hist[po][c];
                    }
                }

                // ---- A: products + w-slide -> W[zi&1] ----
                if (doA) {
                    float pr[16];
                    #pragma unroll
                    for (int m = 0; m < 16; ++m)
                        pr[m] = (cA == 0) ? vx[m]
                              : (cA == 1) ? vy[m]
                              : (cA == 2) ? vx[m] * vx[m]
                              : (cA == 3) ? vy[m] * vy[m]
                                          : vx[m] * vy[m];
                    float o[8];
                    float s = pr[0] + pr[1] + pr[2] + pr[3] + pr[4]
                            + pr[5] + pr[6] + pr[7] + pr[8];
                    o[0] = s;
                    #pragma unroll
                    for (int u = 1; u < 8; ++u) {
                        s += pr[u + 8] - pr[u - 1];
                        o[u] = s;
                    }
                    float* Wd = &Wb[(zi & 1) * WBUFSZ + cA * WPL
                                    + rowA * WSTR + whA * 8];
                    *reinterpret_cast<float4*>(Wd)     = make_float4(o[0], o[1], o[2], o[3]);
                    *reinterpret_cast<float4*>(Wd + 4) = make_float4(o[4], o[5], o[6], o[7]);
                }
                __syncthreads();
            }
        }
    }

    // ---- block reduction: wave shuffle, then 4 partials via LDS ----
    #pragma unroll
    for (int off = 32; off > 0; off >>= 1)
        acc += __shfl_down(acc, off, 64);
    const int wave = t >> 6;
    if ((t & 63) == 0) wsum[wave] = acc;
    __syncthreads();
    if (t == 0) {
        const float s = wsum[0] + wsum[1] + wsum[2] + wsum[3];
        atomicAdd(out, -s * (1.0f / 8192000.0f));
    }
}

extern "C" void kernel_launch(void* const* d_in, const int* in_sizes, int n_in,
                              void* d_out, int out_size, void* d_ws, size_t ws_size,
                              hipStream_t stream)
{
    const float* x = (const float*)d_in[0];
    const float* y = (const float*)d_in[1];
    float* out = (float*)d_out;

    // d_out is poisoned 0xAA before every call; accumulate atomically on zero
    hipMemsetAsync(out, 0, sizeof(float), stream);

    dim3 grid(DIM / TW, DIM / TH, 2 * NCHUNK);  // 10 x 10 x 10 = 1000 blocks
    lncc_kernel<<<grid, 256, 0, stream>>>(x, y, out);
}